// Round 1
// baseline (5802.068 us; speedup 1.0000x reference)
//
#include <hip/hip_runtime.h>
#include <math.h>

#define NBATCH 4096
#define SS 512
#define EE 64
#define MM 16
#define HH 32
#define OUTD 64
#define NSTEPS 5
#define MSTRIDE 514   // 512 + 2: breaks 512 % 32 == 0 bank aliasing across d

__device__ __forceinline__ float sigmoidf_(float x) {
    return 1.0f / (1.0f + __expf(-x));
}

extern "C" __global__ void __launch_bounds__(256)
rpe_fused(const float* __restrict__ input,
          const int* __restrict__ lengths,
          const float* __restrict__ r_w1, const float* __restrict__ r_b1,
          const float* __restrict__ r_w2, const float* __restrict__ r_b2,
          const float* __restrict__ r_w3, const float* __restrict__ r_b3,
          const float* __restrict__ lstm_whh,
          const float* __restrict__ lstm_bih, const float* __restrict__ lstm_bhh,
          const float* __restrict__ proj_w, const float* __restrict__ proj_b,
          const float* __restrict__ w_w1, const float* __restrict__ w_b1,
          const float* __restrict__ w_w2, const float* __restrict__ w_b2,
          const float* __restrict__ w_w3, const float* __restrict__ w_b3,
          const float* __restrict__ empty_vec,
          float* __restrict__ out)
{
    __shared__ float s_mem[MM * MSTRIDE];   // memories, transposed [d][s]
    __shared__ float s_qstar[2 * MM];
    __shared__ float s_c[HH];
    __shared__ float s_h[HH];
    __shared__ float s_gates[4 * HH];
    __shared__ float s_q[MM];
    __shared__ float s_wmax[4];
    __shared__ float s_wsum[4];
    __shared__ float s_rpart[4 * MM];
    __shared__ float s_o1[HH];
    __shared__ float s_o2[HH];

    const int b    = blockIdx.x;
    const int tid  = threadIdx.x;
    const int lane = tid & 63;
    const int wid  = tid >> 6;

    const int len      = lengths[b];
    const int safe_len = len > 0 ? len : 1;

    if (tid < HH) { s_qstar[tid] = 0.0f; s_c[tid] = 0.0f; }

    // ---------------- Phase 1: memories = MLP(input_set[b]) ----------------
    // Each thread computes 2 rows; x kept in VGPRs; weights uniform (s_load).
    #pragma unroll 1
    for (int rr = 0; rr < 2; ++rr) {
        const int r = tid + rr * 256;
        const float4* xp =
            reinterpret_cast<const float4*>(input + ((size_t)b * SS + r) * EE);
        float x[EE];
        #pragma unroll
        for (int i = 0; i < EE / 4; ++i) {
            const float4 v = xp[i];
            x[4*i+0] = v.x; x[4*i+1] = v.y; x[4*i+2] = v.z; x[4*i+3] = v.w;
        }
        float h1[HH];
        #pragma unroll
        for (int j = 0; j < HH; ++j) {
            float acc = r_b1[j];
            #pragma unroll
            for (int i = 0; i < EE; ++i) acc = fmaf(x[i], r_w1[j * EE + i], acc);
            h1[j] = fmaxf(acc, 0.0f);
        }
        float h2[HH];
        #pragma unroll
        for (int j = 0; j < HH; ++j) {
            float acc = r_b2[j];
            #pragma unroll
            for (int k = 0; k < HH; ++k) acc = fmaf(h1[k], r_w2[j * HH + k], acc);
            h2[j] = fmaxf(acc, 0.0f);
        }
        #pragma unroll
        for (int d = 0; d < MM; ++d) {
            float acc = r_b3[d];
            #pragma unroll
            for (int k = 0; k < HH; ++k) acc = fmaf(h2[k], r_w3[d * HH + k], acc);
            s_mem[d * MSTRIDE + r] = acc;   // lane-consecutive: conflict-free
        }
    }
    __syncthreads();

    // ---------------- Phase 2: 5 process steps ----------------
    for (int step = 0; step < NSTEPS; ++step) {
        // LSTM gates: gates = q_star @ whh.T + bih + bhh   (zero input => no wih)
        if (tid < 4 * HH) {
            float acc = lstm_bih[tid] + lstm_bhh[tid];
            #pragma unroll
            for (int k = 0; k < HH; ++k)
                acc = fmaf(lstm_whh[tid * HH + k], s_qstar[k], acc);
            s_gates[tid] = acc;
        }
        __syncthreads();
        if (tid < HH) {
            const float ig = sigmoidf_(s_gates[tid]);
            const float fg = sigmoidf_(s_gates[HH + tid]);
            const float gg = tanhf(s_gates[2 * HH + tid]);
            const float og = sigmoidf_(s_gates[3 * HH + tid]);
            const float c  = fg * s_c[tid] + ig * gg;
            s_c[tid] = c;
            s_h[tid] = og * tanhf(c);
        }
        __syncthreads();
        // q = h @ proj_w.T + proj_b ; also q_star[0:16] = q
        if (tid < MM) {
            float acc = proj_b[tid];
            #pragma unroll
            for (int k = 0; k < HH; ++k)
                acc = fmaf(proj_w[tid * HH + k], s_h[k], acc);
            s_q[tid] = acc;
            s_qstar[tid] = acc;
        }
        __syncthreads();

        // attention: e[s] = mem[s]·q, masked softmax, r = sum a[s]*mem[s]
        float qreg[MM];
        #pragma unroll
        for (int d = 0; d < MM; ++d) qreg[d] = s_q[d];  // broadcast reads

        const int s1 = tid, s2 = tid + 256;
        float e1 = 0.0f, e2 = 0.0f;
        #pragma unroll
        for (int d = 0; d < MM; ++d) {
            e1 = fmaf(s_mem[d * MSTRIDE + s1], qreg[d], e1);
            e2 = fmaf(s_mem[d * MSTRIDE + s2], qreg[d], e2);
        }
        if (s1 >= safe_len) e1 = -1e30f;
        if (s2 >= safe_len) e2 = -1e30f;

        float mv = fmaxf(e1, e2);
        #pragma unroll
        for (int off = 32; off > 0; off >>= 1)
            mv = fmaxf(mv, __shfl_xor(mv, off, 64));
        if (lane == 0) s_wmax[wid] = mv;
        __syncthreads();
        const float maxv = fmaxf(fmaxf(s_wmax[0], s_wmax[1]),
                                 fmaxf(s_wmax[2], s_wmax[3]));

        const float p1 = __expf(e1 - maxv);   // masked -> exp(-huge) = 0
        const float p2 = __expf(e2 - maxv);
        float ds = p1 + p2;
        #pragma unroll
        for (int off = 32; off > 0; off >>= 1)
            ds += __shfl_xor(ds, off, 64);
        if (lane == 0) s_wsum[wid] = ds;

        float rv[MM];
        #pragma unroll
        for (int d = 0; d < MM; ++d) {
            float v = p1 * s_mem[d * MSTRIDE + s1] + p2 * s_mem[d * MSTRIDE + s2];
            #pragma unroll
            for (int off = 32; off > 0; off >>= 1)
                v += __shfl_xor(v, off, 64);
            rv[d] = v;
        }
        if (lane == 0) {
            #pragma unroll
            for (int d = 0; d < MM; ++d) s_rpart[wid * MM + d] = rv[d];
        }
        __syncthreads();
        if (tid < MM) {
            const float denom =
                s_wsum[0] + s_wsum[1] + s_wsum[2] + s_wsum[3];
            const float rval = (s_rpart[tid] + s_rpart[MM + tid] +
                                s_rpart[2 * MM + tid] + s_rpart[3 * MM + tid]) / denom;
            s_qstar[MM + tid] = rval;   // q_star[16:32] = r
        }
        __syncthreads();
    }

    // ---------------- Phase 3: write MLP + empty-set override ----------------
    if (tid < HH) {
        float acc = w_b1[tid];
        #pragma unroll
        for (int k = 0; k < 2 * MM; ++k)
            acc = fmaf(w_w1[tid * 2 * MM + k], s_qstar[k], acc);
        s_o1[tid] = fmaxf(acc, 0.0f);
    }
    __syncthreads();
    if (tid < HH) {
        float acc = w_b2[tid];
        #pragma unroll
        for (int k = 0; k < HH; ++k)
            acc = fmaf(w_w2[tid * HH + k], s_o1[k], acc);
        s_o2[tid] = fmaxf(acc, 0.0f);
    }
    __syncthreads();
    if (tid < OUTD) {
        float res;
        if (len > 0) {
            float acc = w_b3[tid];
            #pragma unroll
            for (int k = 0; k < HH; ++k)
                acc = fmaf(w_w3[tid * HH + k], s_o2[k], acc);
            res = acc;
        } else {
            res = empty_vec[tid];
        }
        out[(size_t)b * OUTD + tid] = res;
    }
}

extern "C" void kernel_launch(void* const* d_in, const int* in_sizes, int n_in,
                              void* d_out, int out_size, void* d_ws, size_t ws_size,
                              hipStream_t stream)
{
    const float* input   = (const float*)d_in[0];
    const int*   lengths = (const int*)  d_in[1];
    const float* r_w1    = (const float*)d_in[2];
    const float* r_b1    = (const float*)d_in[3];
    const float* r_w2    = (const float*)d_in[4];
    const float* r_b2    = (const float*)d_in[5];
    const float* r_w3    = (const float*)d_in[6];
    const float* r_b3    = (const float*)d_in[7];
    // d_in[8] = lstm_wih: multiplied by zero input in the reference -> unused
    const float* whh     = (const float*)d_in[9];
    const float* bih     = (const float*)d_in[10];
    const float* bhh     = (const float*)d_in[11];
    const float* proj_w  = (const float*)d_in[12];
    const float* proj_b  = (const float*)d_in[13];
    const float* w_w1    = (const float*)d_in[14];
    const float* w_b1    = (const float*)d_in[15];
    const float* w_w2    = (const float*)d_in[16];
    const float* w_b2    = (const float*)d_in[17];
    const float* w_w3    = (const float*)d_in[18];
    const float* w_b3    = (const float*)d_in[19];
    const float* empty_v = (const float*)d_in[20];
    float* outp = (float*)d_out;

    rpe_fused<<<NBATCH, 256, 0, stream>>>(
        input, lengths,
        r_w1, r_b1, r_w2, r_b2, r_w3, r_b3,
        whh, bih, bhh,
        proj_w, proj_b,
        w_w1, w_b1, w_w2, w_b2, w_w3, w_b3,
        empty_v, outp);
}

// Round 2
// 1577.521 us; speedup vs baseline: 3.6780x; 3.6780x over previous
//
#include <hip/hip_runtime.h>
#include <math.h>

#define NBATCH 4096
#define SS 512
#define EE 64
#define MM 16
#define HH 32
#define OUTD 64
#define NSTEPS 5
#define MSTRIDE 514   // 512 + 2: breaks 512 % 32 == 0 bank aliasing across d

__device__ __forceinline__ float fast_sigmoid(float x) {
    return 1.0f / (1.0f + __expf(-x));
}
__device__ __forceinline__ float fast_tanh(float x) {
    // tanh(x) = 1 - 2/(exp(2x)+1)
    return 1.0f - 2.0f / (__expf(2.0f * x) + 1.0f);
}

extern "C" __global__ void __launch_bounds__(256, 3)
rpe_fused(const float* __restrict__ input,
          const int* __restrict__ lengths,
          const float* __restrict__ r_w1, const float* __restrict__ r_b1,
          const float* __restrict__ r_w2, const float* __restrict__ r_b2,
          const float* __restrict__ r_w3, const float* __restrict__ r_b3,
          const float* __restrict__ lstm_whh,
          const float* __restrict__ lstm_bih, const float* __restrict__ lstm_bhh,
          const float* __restrict__ proj_w, const float* __restrict__ proj_b,
          const float* __restrict__ w_w1, const float* __restrict__ w_b1,
          const float* __restrict__ w_w2, const float* __restrict__ w_b2,
          const float* __restrict__ w_w3, const float* __restrict__ w_b3,
          const float* __restrict__ empty_vec,
          float* __restrict__ out)
{
    __shared__ float s_mem[MM * MSTRIDE];   // memories, transposed [d][s]
    // phase-1 weights staged in LDS (broadcast reads are conflict-free)
    __shared__ float s_w1[HH * EE];         // 2048
    __shared__ float s_w2[HH * HH];         // 1024
    __shared__ float s_w3[MM * HH];         // 512
    __shared__ float s_b1[HH];
    __shared__ float s_b2[HH];
    __shared__ float s_b3[MM];

    __shared__ float s_qstar[2 * MM];
    __shared__ float s_c[HH];
    __shared__ float s_h[HH];
    __shared__ float s_gates[4 * HH];
    __shared__ float s_q[MM];
    __shared__ float s_wmax[4];
    __shared__ float s_wsum[4];
    __shared__ float s_rpart[4 * MM];
    __shared__ float s_o1[HH];
    __shared__ float s_o2[HH];

    const int b    = blockIdx.x;
    const int tid  = threadIdx.x;
    const int lane = tid & 63;
    const int wid  = tid >> 6;

    const int len      = lengths[b];
    const int safe_len = len > 0 ? len : 1;

    // ------------ Stage phase-1 weights into LDS (cooperative, float4) ------
    {
        float4*       w1d = reinterpret_cast<float4*>(s_w1);
        const float4* w1s = reinterpret_cast<const float4*>(r_w1);
        w1d[tid]       = w1s[tid];        // 512 float4 total
        w1d[tid + 256] = w1s[tid + 256];
        float4*       w2d = reinterpret_cast<float4*>(s_w2);
        const float4* w2s = reinterpret_cast<const float4*>(r_w2);
        w2d[tid] = w2s[tid];              // 256 float4
        if (tid < 128) {
            float4*       w3d = reinterpret_cast<float4*>(s_w3);
            const float4* w3s = reinterpret_cast<const float4*>(r_w3);
            w3d[tid] = w3s[tid];          // 128 float4
        }
        if (tid < HH) { s_b1[tid] = r_b1[tid]; s_b2[tid] = r_b2[tid]; }
        if (tid < MM) { s_b3[tid] = r_b3[tid]; }
        if (tid < HH) { s_qstar[tid] = 0.0f; s_c[tid] = 0.0f; }
    }
    __syncthreads();

    // ---------------- Phase 1: memories = MLP(input_set[b]) ----------------
    const float4* w1v = reinterpret_cast<const float4*>(s_w1);
    const float4* w2v = reinterpret_cast<const float4*>(s_w2);
    const float4* w3v = reinterpret_cast<const float4*>(s_w3);

    #pragma unroll 1
    for (int rr = 0; rr < 2; ++rr) {
        const int r = tid + rr * 256;
        const float4* xp =
            reinterpret_cast<const float4*>(input + ((size_t)b * SS + r) * EE);
        float x[EE];
        #pragma unroll
        for (int i = 0; i < EE / 4; ++i) {
            const float4 v = xp[i];
            x[4*i+0] = v.x; x[4*i+1] = v.y; x[4*i+2] = v.z; x[4*i+3] = v.w;
        }
        float h1[HH];
        #pragma unroll
        for (int j = 0; j < HH; ++j) {
            float acc = s_b1[j];
            #pragma unroll
            for (int q = 0; q < EE / 4; ++q) {
                const float4 w = w1v[j * (EE / 4) + q];
                acc = fmaf(x[4*q+0], w.x, acc);
                acc = fmaf(x[4*q+1], w.y, acc);
                acc = fmaf(x[4*q+2], w.z, acc);
                acc = fmaf(x[4*q+3], w.w, acc);
            }
            h1[j] = fmaxf(acc, 0.0f);
        }
        float h2[HH];
        #pragma unroll
        for (int j = 0; j < HH; ++j) {
            float acc = s_b2[j];
            #pragma unroll
            for (int q = 0; q < HH / 4; ++q) {
                const float4 w = w2v[j * (HH / 4) + q];
                acc = fmaf(h1[4*q+0], w.x, acc);
                acc = fmaf(h1[4*q+1], w.y, acc);
                acc = fmaf(h1[4*q+2], w.z, acc);
                acc = fmaf(h1[4*q+3], w.w, acc);
            }
            h2[j] = fmaxf(acc, 0.0f);
        }
        #pragma unroll
        for (int d = 0; d < MM; ++d) {
            float acc = s_b3[d];
            #pragma unroll
            for (int q = 0; q < HH / 4; ++q) {
                const float4 w = w3v[d * (HH / 4) + q];
                acc = fmaf(h2[4*q+0], w.x, acc);
                acc = fmaf(h2[4*q+1], w.y, acc);
                acc = fmaf(h2[4*q+2], w.z, acc);
                acc = fmaf(h2[4*q+3], w.w, acc);
            }
            s_mem[d * MSTRIDE + r] = acc;   // lane-consecutive: conflict-free
        }
    }
    __syncthreads();

    // ---------------- Phase 2: 5 process steps ----------------
    for (int step = 0; step < NSTEPS; ++step) {
        // LSTM gates: gates = q_star @ whh.T + bih + bhh   (zero input => no wih)
        if (tid < 4 * HH) {
            float acc = lstm_bih[tid] + lstm_bhh[tid];
            #pragma unroll
            for (int k = 0; k < HH; ++k)
                acc = fmaf(lstm_whh[tid * HH + k], s_qstar[k], acc);
            s_gates[tid] = acc;
        }
        __syncthreads();
        if (tid < HH) {
            const float ig = fast_sigmoid(s_gates[tid]);
            const float fg = fast_sigmoid(s_gates[HH + tid]);
            const float gg = fast_tanh(s_gates[2 * HH + tid]);
            const float og = fast_sigmoid(s_gates[3 * HH + tid]);
            const float c  = fg * s_c[tid] + ig * gg;
            s_c[tid] = c;
            s_h[tid] = og * fast_tanh(c);
        }
        __syncthreads();
        // q = h @ proj_w.T + proj_b ; also q_star[0:16] = q
        if (tid < MM) {
            float acc = proj_b[tid];
            #pragma unroll
            for (int k = 0; k < HH; ++k)
                acc = fmaf(proj_w[tid * HH + k], s_h[k], acc);
            s_q[tid] = acc;
            s_qstar[tid] = acc;
        }
        __syncthreads();

        // attention: e[s] = mem[s]·q, masked softmax, r = sum a[s]*mem[s]
        float qreg[MM];
        #pragma unroll
        for (int d = 0; d < MM; ++d) qreg[d] = s_q[d];  // broadcast reads

        const int s1 = tid, s2 = tid + 256;
        float m1[MM], m2[MM];
        #pragma unroll
        for (int d = 0; d < MM; ++d) {
            m1[d] = s_mem[d * MSTRIDE + s1];
            m2[d] = s_mem[d * MSTRIDE + s2];
        }
        float e1 = 0.0f, e2 = 0.0f;
        #pragma unroll
        for (int d = 0; d < MM; ++d) {
            e1 = fmaf(m1[d], qreg[d], e1);
            e2 = fmaf(m2[d], qreg[d], e2);
        }
        if (s1 >= safe_len) e1 = -1e30f;
        if (s2 >= safe_len) e2 = -1e30f;

        float mv = fmaxf(e1, e2);
        #pragma unroll
        for (int off = 32; off > 0; off >>= 1)
            mv = fmaxf(mv, __shfl_xor(mv, off, 64));
        if (lane == 0) s_wmax[wid] = mv;
        __syncthreads();
        const float maxv = fmaxf(fmaxf(s_wmax[0], s_wmax[1]),
                                 fmaxf(s_wmax[2], s_wmax[3]));

        const float p1 = __expf(e1 - maxv);   // masked -> exp(-huge) = 0
        const float p2 = __expf(e2 - maxv);
        float ds = p1 + p2;
        #pragma unroll
        for (int off = 32; off > 0; off >>= 1)
            ds += __shfl_xor(ds, off, 64);
        if (lane == 0) s_wsum[wid] = ds;

        float rv[MM];
        #pragma unroll
        for (int d = 0; d < MM; ++d) {
            float v = fmaf(p1, m1[d], p2 * m2[d]);
            #pragma unroll
            for (int off = 32; off > 0; off >>= 1)
                v += __shfl_xor(v, off, 64);
            rv[d] = v;
        }
        if (lane == 0) {
            #pragma unroll
            for (int d = 0; d < MM; ++d) s_rpart[wid * MM + d] = rv[d];
        }
        __syncthreads();
        if (tid < MM) {
            const float denom =
                s_wsum[0] + s_wsum[1] + s_wsum[2] + s_wsum[3];
            const float rval = (s_rpart[tid] + s_rpart[MM + tid] +
                                s_rpart[2 * MM + tid] + s_rpart[3 * MM + tid]) / denom;
            s_qstar[MM + tid] = rval;   // q_star[16:32] = r
        }
        __syncthreads();
    }

    // ---------------- Phase 3: write MLP + empty-set override ----------------
    if (tid < HH) {
        float acc = w_b1[tid];
        #pragma unroll
        for (int k = 0; k < 2 * MM; ++k)
            acc = fmaf(w_w1[tid * 2 * MM + k], s_qstar[k], acc);
        s_o1[tid] = fmaxf(acc, 0.0f);
    }
    __syncthreads();
    if (tid < HH) {
        float acc = w_b2[tid];
        #pragma unroll
        for (int k = 0; k < HH; ++k)
            acc = fmaf(w_w2[tid * HH + k], s_o1[k], acc);
        s_o2[tid] = fmaxf(acc, 0.0f);
    }
    __syncthreads();
    if (tid < OUTD) {
        float res;
        if (len > 0) {
            float acc = w_b3[tid];
            #pragma unroll
            for (int k = 0; k < HH; ++k)
                acc = fmaf(w_w3[tid * HH + k], s_o2[k], acc);
            res = acc;
        } else {
            res = empty_vec[tid];
        }
        out[(size_t)b * OUTD + tid] = res;
    }
}

extern "C" void kernel_launch(void* const* d_in, const int* in_sizes, int n_in,
                              void* d_out, int out_size, void* d_ws, size_t ws_size,
                              hipStream_t stream)
{
    const float* input   = (const float*)d_in[0];
    const int*   lengths = (const int*)  d_in[1];
    const float* r_w1    = (const float*)d_in[2];
    const float* r_b1    = (const float*)d_in[3];
    const float* r_w2    = (const float*)d_in[4];
    const float* r_b2    = (const float*)d_in[5];
    const float* r_w3    = (const float*)d_in[6];
    const float* r_b3    = (const float*)d_in[7];
    // d_in[8] = lstm_wih: multiplied by zero input in the reference -> unused
    const float* whh     = (const float*)d_in[9];
    const float* bih     = (const float*)d_in[10];
    const float* bhh     = (const float*)d_in[11];
    const float* proj_w  = (const float*)d_in[12];
    const float* proj_b  = (const float*)d_in[13];
    const float* w_w1    = (const float*)d_in[14];
    const float* w_b1    = (const float*)d_in[15];
    const float* w_w2    = (const float*)d_in[16];
    const float* w_b2    = (const float*)d_in[17];
    const float* w_w3    = (const float*)d_in[18];
    const float* w_b3    = (const float*)d_in[19];
    const float* empty_v = (const float*)d_in[20];
    float* outp = (float*)d_out;

    rpe_fused<<<NBATCH, 256, 0, stream>>>(
        input, lengths,
        r_w1, r_b1, r_w2, r_b2, r_w3, r_b3,
        whh, bih, bhh,
        proj_w, proj_b,
        w_w1, w_b1, w_w2, w_b2, w_w3, w_b3,
        empty_v, outp);
}